// Round 7
// baseline (183.523 us; speedup 1.0000x reference)
//
#include <hip/hip_runtime.h>
#include <hip/hip_cooperative_groups.h>
#include <math.h>

namespace cg = cooperative_groups;

// LinearAttention: L=4096, B=4, H=8, D=Dv=64, fp32.
// out[l,b,h,e] = (phiQ[l,bh,:] . kv[bh,:,e]) / (phiQ[l,bh,:] . ksum[bh,:] + eps)
// kv[bh,d,e] = sum_l phiK[l,bh,d] * V[l,bh,e]   (GLOBAL sum, not causal)
// phi(x) = elu(x)+1 = x>0 ? x+1 : exp(x)

#define L_TOT 4096
#define NBH   32            // B*H
#define ROWSTRIDE 2048      // B*H*D floats between consecutive l
#define KVSZ  4160          // 64*64 kv + 64 ksum
#define NCHUNK 16           // fixed: 16 chunks x 256 rows
#define EPS_  1e-6f

__device__ __forceinline__ float phi_(float x) {
    return x > 0.0f ? x + 1.0f : __expf(x);
}

// =================== FUSED cooperative kernel ===================
// grid = 512 (16 x 32bh) x 256 thr, LDS 80 KB -> exactly 2 blocks/CU.
// Phase A: partial kv+ksum for (chunk=bid>>5, bh=bid&31) -> ws.
// grid.sync()
// Phase C: (tile-group=bid>>5, bh): sum 16 partials into LDS skv + reg ksum,
// stage phiQ^T swizzled, register-tiled 64x64x64 GEMM per wave, store out.
__global__ __launch_bounds__(256) void fused_kernel(
    const float* __restrict__ K, const float* __restrict__ V,
    const float* __restrict__ Q, float* __restrict__ part,
    float* __restrict__ out)
{
    __shared__ __align__(16) float sm[20480];      // 80 KB exactly

    const int tid  = threadIdx.x;
    const int w    = tid >> 6;          // wave 0..3
    const int lane = tid & 63;
    const int bid  = blockIdx.x;
    const int c    = bid >> 5;          // 0..15
    const int bh   = bid & 31;

    const int d0 = (lane >> 3) * 8;     // lane's 8 rows (d) in 64x64 tiles
    const int e0 = (lane & 7) * 8;      // lane's 8 cols (e)
    const int sr = tid >> 4;            // staging row 0..15 (and +16)
    const int sc = (tid & 15) * 4;      // staging col (float4)

    const size_t bh_off = (size_t)bh * 64;

    // ---------------- Phase A: partial kv + ksum ----------------
    {
        float (*phk)[64] = (float(*)[64])sm;           // [32][64]
        float (*vvv)[64] = (float(*)[64])(sm + 2048);  // [32][64]

        float acc[8][8];
        #pragma unroll
        for (int i = 0; i < 8; ++i)
            #pragma unroll
            for (int j = 0; j < 8; ++j) acc[i][j] = 0.f;
        float ks[8] = {0.f,0.f,0.f,0.f,0.f,0.f,0.f,0.f};

        const int l0c = c * 256;
        size_t base0 = (size_t)(l0c + sr) * ROWSTRIDE + bh_off + sc;
        float4 ka = *(const float4*)(K + base0);
        float4 va = *(const float4*)(V + base0);
        float4 kb = *(const float4*)(K + base0 + 16 * ROWSTRIDE);
        float4 vb = *(const float4*)(V + base0 + 16 * ROWSTRIDE);

        #pragma unroll 1
        for (int rnd = 0; rnd < 8; ++rnd) {
            float4 pa, pb2;
            pa.x  = phi_(ka.x); pa.y  = phi_(ka.y); pa.z  = phi_(ka.z); pa.w  = phi_(ka.w);
            pb2.x = phi_(kb.x); pb2.y = phi_(kb.y); pb2.z = phi_(kb.z); pb2.w = phi_(kb.w);
            __syncthreads();                 // previous round's LDS reads done
            *(float4*)&phk[sr][sc]      = pa;
            *(float4*)&phk[sr + 16][sc] = pb2;
            *(float4*)&vvv[sr][sc]      = va;
            *(float4*)&vvv[sr + 16][sc] = vb;
            __syncthreads();

            if (rnd < 7) {                   // prefetch next round
                base0 += 32 * ROWSTRIDE;
                ka = *(const float4*)(K + base0);
                va = *(const float4*)(V + base0);
                kb = *(const float4*)(K + base0 + 16 * ROWSTRIDE);
                vb = *(const float4*)(V + base0 + 16 * ROWSTRIDE);
            }

            #pragma unroll
            for (int r = 0; r < 8; ++r) {
                const int rr = w * 8 + r;
                float4 a0 = *(const float4*)&phk[rr][d0];
                float4 a1 = *(const float4*)&phk[rr][d0 + 4];
                float4 b0 = *(const float4*)&vvv[rr][e0];
                float4 b1 = *(const float4*)&vvv[rr][e0 + 4];
                float av[8] = {a0.x,a0.y,a0.z,a0.w,a1.x,a1.y,a1.z,a1.w};
                float bv[8] = {b0.x,b0.y,b0.z,b0.w,b1.x,b1.y,b1.z,b1.w};
                #pragma unroll
                for (int i = 0; i < 8; ++i) {
                    ks[i] += av[i];
                    #pragma unroll
                    for (int j = 0; j < 8; ++j)
                        acc[i][j] = fmaf(av[i], bv[j], acc[i][j]);
                }
            }
        }

        // block-reduce 4 waves -> part[(c,bh)]
        __syncthreads();
        if (w > 0) {
            float* sl = sm + (w - 1) * 4160;
            #pragma unroll
            for (int i = 0; i < 8; ++i) {
                *(float4*)&sl[(d0 + i) * 64 + e0]     = make_float4(acc[i][0], acc[i][1], acc[i][2], acc[i][3]);
                *(float4*)&sl[(d0 + i) * 64 + e0 + 4] = make_float4(acc[i][4], acc[i][5], acc[i][6], acc[i][7]);
            }
            if (e0 == 0) {
                #pragma unroll
                for (int i = 0; i < 8; ++i) sl[4096 + d0 + i] = ks[i];
            }
        }
        __syncthreads();
        if (w == 0) {
            float* pb = part + ((size_t)c * NBH + bh) * KVSZ;
            #pragma unroll
            for (int i = 0; i < 8; ++i) {
                #pragma unroll
                for (int jq = 0; jq < 2; ++jq) {
                    const int off = (d0 + i) * 64 + e0 + jq * 4;
                    float4 s0 = *(const float4*)&sm[off];
                    float4 s1 = *(const float4*)&sm[4160 + off];
                    float4 s2 = *(const float4*)&sm[8320 + off];
                    float4 o;
                    o.x = acc[i][jq*4+0] + s0.x + s1.x + s2.x;
                    o.y = acc[i][jq*4+1] + s0.y + s1.y + s2.y;
                    o.z = acc[i][jq*4+2] + s0.z + s1.z + s2.z;
                    o.w = acc[i][jq*4+3] + s0.w + s1.w + s2.w;
                    *(float4*)&pb[off] = o;
                }
            }
            if (e0 == 0) {
                #pragma unroll
                for (int i = 0; i < 8; ++i) {
                    const int dd = 4096 + d0 + i;
                    pb[dd] = ks[i] + sm[dd] + sm[4160 + dd] + sm[8320 + dd];
                }
            }
        }
        __threadfence();
    }

    cg::this_grid().sync();

    // ---------------- Phase C: output GEMM ----------------
    {
        float* __restrict__ pw  = sm + w * 4096;       // per-wave phiQ^T (swz)
        float* __restrict__ skv = sm + 16384;          // kv[d][e], 16 KB

        // per-lane summed ksum (d = lane), broadcast via shfl in the loop
        float ksreg = 0.f;
        #pragma unroll
        for (int cc = 0; cc < NCHUNK; ++cc)
            ksreg += part[((size_t)cc * NBH + bh) * KVSZ + 4096 + lane];

        // sum 16 kv partials into skv (float4 lanes, coalesced, L2-resident)
        {
            float4* __restrict__ sk4 = (float4*)skv;
            #pragma unroll
            for (int k = 0; k < 4; ++k) {
                const int idx = tid + k * 256;
                float4 s = make_float4(0.f, 0.f, 0.f, 0.f);
                #pragma unroll
                for (int cc = 0; cc < NCHUNK; ++cc) {
                    const float4 v = *(const float4*)(part + ((size_t)cc * NBH + bh) * KVSZ + idx * 4);
                    s.x += v.x; s.y += v.y; s.z += v.z; s.w += v.w;
                }
                sk4[idx] = s;
            }
        }

        // stage phi(Q)^T with float4-block XOR swizzle
        const int tile0 = c * 256 + w * 64;            // wave's 64 tokens
        {
            const int s = lane >> 4;
            const int cq = (lane & 15) * 4;
            #pragma unroll
            for (int r = 0; r < 16; ++r) {
                const int t = r * 4 + s;
                float4 q4 = *(const float4*)(Q + (size_t)(tile0 + t) * ROWSTRIDE + bh_off + cq);
                float p0 = phi_(q4.x), p1 = phi_(q4.y), p2 = phi_(q4.z), p3 = phi_(q4.w);
                pw[(cq + 0) * 64 + ((r ^ ((cq + 0) & 15)) << 2) + s] = p0;
                pw[(cq + 1) * 64 + ((r ^ ((cq + 1) & 15)) << 2) + s] = p1;
                pw[(cq + 2) * 64 + ((r ^ ((cq + 2) & 15)) << 2) + s] = p2;
                pw[(cq + 3) * 64 + ((r ^ ((cq + 3) & 15)) << 2) + s] = p3;
            }
        }
        __syncthreads();

        const int t0 = (lane >> 3) * 8;      // lane's 8 tokens
        const int jb = t0 >> 2;              // even f4-block index

        float acc[8][8];
        #pragma unroll
        for (int i = 0; i < 8; ++i)
            #pragma unroll
            for (int j = 0; j < 8; ++j) acc[i][j] = 0.f;
        float den[8] = {0.f,0.f,0.f,0.f,0.f,0.f,0.f,0.f};

        #pragma unroll 4
        for (int d = 0; d < 64; ++d) {
            const int x = d & 15;
            float4 a0 = *(const float4*)&pw[d * 64 + ((jb       ^ x) << 2)];
            float4 a1 = *(const float4*)&pw[d * 64 + (((jb + 1) ^ x) << 2)];
            float4 b0 = *(const float4*)&skv[d * 64 + e0];
            float4 b1 = *(const float4*)&skv[d * 64 + e0 + 4];
            const float ksv = __shfl(ksreg, d, 64);
            float av[8] = {a0.x,a0.y,a0.z,a0.w,a1.x,a1.y,a1.z,a1.w};
            float bv[8] = {b0.x,b0.y,b0.z,b0.w,b1.x,b1.y,b1.z,b1.w};
            #pragma unroll
            for (int i = 0; i < 8; ++i) {
                den[i] = fmaf(av[i], ksv, den[i]);
                #pragma unroll
                for (int j = 0; j < 8; ++j)
                    acc[i][j] = fmaf(av[i], bv[j], acc[i][j]);
            }
        }

        #pragma unroll
        for (int i = 0; i < 8; ++i) {
            const float inv = 1.0f / (den[i] + EPS_);
            float* op = out + (size_t)(tile0 + t0 + i) * ROWSTRIDE + bh_off + e0;
            *(float4*)op       = make_float4(acc[i][0]*inv, acc[i][1]*inv,
                                             acc[i][2]*inv, acc[i][3]*inv);
            *(float4*)(op + 4) = make_float4(acc[i][4]*inv, acc[i][5]*inv,
                                             acc[i][6]*inv, acc[i][7]*inv);
        }
    }
}

// =================== Fallback path (R5 three-kernel) ===================
__global__ __launch_bounds__(256) void kv_partial_kernel(
    const float* __restrict__ K, const float* __restrict__ V,
    float* __restrict__ part, int Lc)
{
    __shared__ float sm[12480];
    float (*phk)[64] = (float(*)[64])sm;
    float (*vvv)[64] = (float(*)[64])(sm + 2048);

    const int tid = threadIdx.x;
    const int w = tid >> 6, lane = tid & 63;
    const int c = blockIdx.x, bh = blockIdx.y;
    const int l0c = c * Lc;
    const int lend = min(l0c + Lc, L_TOT);
    const int d0 = (lane >> 3) * 8, e0 = (lane & 7) * 8;
    const int sr = tid >> 4, sc = (tid & 15) * 4;

    float acc[8][8];
    #pragma unroll
    for (int i = 0; i < 8; ++i)
        #pragma unroll
        for (int j = 0; j < 8; ++j) acc[i][j] = 0.f;
    float ks[8] = {0.f,0.f,0.f,0.f,0.f,0.f,0.f,0.f};
    const size_t bh_off = (size_t)bh * 64;

    float4 z4 = make_float4(0.f, 0.f, 0.f, 0.f);
    bool ok0 = (l0c + sr) < lend, ok1 = (l0c + sr + 16) < lend;
    float4 ka = z4, kb = z4, va = z4, vb = z4;
    if (ok0) { const size_t b = (size_t)(l0c + sr) * ROWSTRIDE + bh_off + sc;
               ka = *(const float4*)(K + b); va = *(const float4*)(V + b); }
    if (ok1) { const size_t b = (size_t)(l0c + sr + 16) * ROWSTRIDE + bh_off + sc;
               kb = *(const float4*)(K + b); vb = *(const float4*)(V + b); }

    for (int l0 = l0c; l0 < lend; l0 += 32) {
        float4 pa = z4, pb2 = z4;
        if (ok0) { pa.x = phi_(ka.x); pa.y = phi_(ka.y); pa.z = phi_(ka.z); pa.w = phi_(ka.w); }
        if (ok1) { pb2.x = phi_(kb.x); pb2.y = phi_(kb.y); pb2.z = phi_(kb.z); pb2.w = phi_(kb.w); }
        __syncthreads();
        *(float4*)&phk[sr][sc] = pa;      *(float4*)&phk[sr + 16][sc] = pb2;
        *(float4*)&vvv[sr][sc] = va;      *(float4*)&vvv[sr + 16][sc] = vb;
        __syncthreads();
        ok0 = (l0 + 32 + sr) < lend;  ok1 = (l0 + 32 + sr + 16) < lend;
        ka = z4; kb = z4; va = z4; vb = z4;
        if (ok0) { const size_t b = (size_t)(l0 + 32 + sr) * ROWSTRIDE + bh_off + sc;
                   ka = *(const float4*)(K + b); va = *(const float4*)(V + b); }
        if (ok1) { const size_t b = (size_t)(l0 + 32 + sr + 16) * ROWSTRIDE + bh_off + sc;
                   kb = *(const float4*)(K + b); vb = *(const float4*)(V + b); }
        #pragma unroll
        for (int r = 0; r < 8; ++r) {
            const int rr = w * 8 + r;
            float4 a0 = *(const float4*)&phk[rr][d0];
            float4 a1 = *(const float4*)&phk[rr][d0 + 4];
            float4 b0 = *(const float4*)&vvv[rr][e0];
            float4 b1 = *(const float4*)&vvv[rr][e0 + 4];
            float av[8] = {a0.x,a0.y,a0.z,a0.w,a1.x,a1.y,a1.z,a1.w};
            float bv[8] = {b0.x,b0.y,b0.z,b0.w,b1.x,b1.y,b1.z,b1.w};
            #pragma unroll
            for (int i = 0; i < 8; ++i) {
                ks[i] += av[i];
                #pragma unroll
                for (int j = 0; j < 8; ++j) acc[i][j] = fmaf(av[i], bv[j], acc[i][j]);
            }
        }
    }
    __syncthreads();
    if (w > 0) {
        float* sl = sm + (w - 1) * 4160;
        #pragma unroll
        for (int i = 0; i < 8; ++i) {
            *(float4*)&sl[(d0 + i) * 64 + e0]     = make_float4(acc[i][0], acc[i][1], acc[i][2], acc[i][3]);
            *(float4*)&sl[(d0 + i) * 64 + e0 + 4] = make_float4(acc[i][4], acc[i][5], acc[i][6], acc[i][7]);
        }
        if (e0 == 0) {
            #pragma unroll
            for (int i = 0; i < 8; ++i) sl[4096 + d0 + i] = ks[i];
        }
    }
    __syncthreads();
    if (w == 0) {
        float* pb = part + ((size_t)c * NBH + bh) * KVSZ;
        #pragma unroll
        for (int i = 0; i < 8; ++i) {
            #pragma unroll
            for (int jq = 0; jq < 2; ++jq) {
                const int off = (d0 + i) * 64 + e0 + jq * 4;
                float4 s0 = *(const float4*)&sm[off];
                float4 s1 = *(const float4*)&sm[4160 + off];
                float4 s2 = *(const float4*)&sm[8320 + off];
                float4 o;
                o.x = acc[i][jq*4+0] + s0.x + s1.x + s2.x;
                o.y = acc[i][jq*4+1] + s0.y + s1.y + s2.y;
                o.z = acc[i][jq*4+2] + s0.z + s1.z + s2.z;
                o.w = acc[i][jq*4+3] + s0.w + s1.w + s2.w;
                *(float4*)&pb[off] = o;
            }
        }
        if (e0 == 0) {
            #pragma unroll
            for (int i = 0; i < 8; ++i) {
                const int dd = 4096 + d0 + i;
                pb[dd] = ks[i] + sm[dd] + sm[4160 + dd] + sm[8320 + dd];
            }
        }
    }
}

__global__ __launch_bounds__(256) void kv_reduce_kernel(
    const float* __restrict__ part, float* __restrict__ fin, int nchunk)
{
    const int i4 = blockIdx.x * 256 + threadIdx.x;
    if (i4 >= (NBH * KVSZ) / 4) return;
    const float4* p4 = (const float4*)part;
    float4 s = make_float4(0.f, 0.f, 0.f, 0.f);
    for (int cc = 0; cc < nchunk; ++cc) {
        float4 v = p4[(size_t)cc * (NBH * KVSZ / 4) + i4];
        s.x += v.x; s.y += v.y; s.z += v.z; s.w += v.w;
    }
    ((float4*)fin)[i4] = s;
}

__global__ __launch_bounds__(256) void attn_out_kernel(
    const float* __restrict__ Q, const float* __restrict__ fin,
    float* __restrict__ out)
{
    __shared__ __align__(16) float pqT[4][4096];
    __shared__ __align__(16) float skv[4096];

    const int tid = threadIdx.x, lane = tid & 63, w = tid >> 6;
    const int bh = blockIdx.x & 31;
    const int tile0 = (blockIdx.x >> 5) * 256 + w * 64;
    const float* __restrict__ fb = fin + (size_t)bh * KVSZ;
    float* __restrict__ pw = pqT[w];

    {
        const float4* __restrict__ fb4 = (const float4*)fb;
        float4* __restrict__ sk4 = (float4*)skv;
        #pragma unroll
        for (int k = 0; k < 4; ++k) sk4[tid + k * 256] = fb4[tid + k * 256];
    }

    {
        const int s = lane >> 4, cq = (lane & 15) * 4;
        #pragma unroll
        for (int r = 0; r < 16; ++r) {
            const int t = r * 4 + s;
            float4 q4 = *(const float4*)(Q + (size_t)(tile0 + t) * ROWSTRIDE + (size_t)bh * 64 + cq);
            float p0 = phi_(q4.x), p1 = phi_(q4.y), p2 = phi_(q4.z), p3 = phi_(q4.w);
            pw[(cq + 0) * 64 + ((r ^ ((cq + 0) & 15)) << 2) + s] = p0;
            pw[(cq + 1) * 64 + ((r ^ ((cq + 1) & 15)) << 2) + s] = p1;
            pw[(cq + 2) * 64 + ((r ^ ((cq + 2) & 15)) << 2) + s] = p2;
            pw[(cq + 3) * 64 + ((r ^ ((cq + 3) & 15)) << 2) + s] = p3;
        }
    }
    __syncthreads();

    const int t0 = (lane >> 3) * 8, e0 = (lane & 7) * 8, jb = t0 >> 2;
    float acc[8][8];
    #pragma unroll
    for (int i = 0; i < 8; ++i)
        #pragma unroll
        for (int j = 0; j < 8; ++j) acc[i][j] = 0.f;
    float den[8] = {0.f,0.f,0.f,0.f,0.f,0.f,0.f,0.f};

    #pragma unroll 4
    for (int d = 0; d < 64; ++d) {
        const int x = d & 15;
        float4 a0 = *(const float4*)&pw[d * 64 + ((jb       ^ x) << 2)];
        float4 a1 = *(const float4*)&pw[d * 64 + (((jb + 1) ^ x) << 2)];
        float4 b0 = *(const float4*)&skv[d * 64 + e0];
        float4 b1 = *(const float4*)&skv[d * 64 + e0 + 4];
        const float ksv = fb[4096 + d];
        float av[8] = {a0.x,a0.y,a0.z,a0.w,a1.x,a1.y,a1.z,a1.w};
        float bv[8] = {b0.x,b0.y,b0.z,b0.w,b1.x,b1.y,b1.z,b1.w};
        #pragma unroll
        for (int i = 0; i < 8; ++i) {
            den[i] = fmaf(av[i], ksv, den[i]);
            #pragma unroll
            for (int j = 0; j < 8; ++j) acc[i][j] = fmaf(av[i], bv[j], acc[i][j]);
        }
    }
    #pragma unroll
    for (int i = 0; i < 8; ++i) {
        const float inv = 1.0f / (den[i] + EPS_);
        float* op = out + (size_t)(tile0 + t0 + i) * ROWSTRIDE + (size_t)bh * 64 + e0;
        *(float4*)op       = make_float4(acc[i][0]*inv, acc[i][1]*inv, acc[i][2]*inv, acc[i][3]*inv);
        *(float4*)(op + 4) = make_float4(acc[i][4]*inv, acc[i][5]*inv, acc[i][6]*inv, acc[i][7]*inv);
    }
}

extern "C" void kernel_launch(void* const* d_in, const int* in_sizes, int n_in,
                              void* d_out, int out_size, void* d_ws, size_t ws_size,
                              hipStream_t stream) {
    const float* Q = (const float*)d_in[0];
    const float* K = (const float*)d_in[1];
    const float* V = (const float*)d_in[2];
    float* outp = (float*)d_out;
    float* ws   = (float*)d_ws;

    const size_t slab = (size_t)NBH * KVSZ;              // 133120 floats
    const size_t need = (size_t)NCHUNK * slab * sizeof(float);   // 8.5 MB

    if (ws_size >= need) {
        float* part = ws;
        void* args[] = {(void*)&K, (void*)&V, (void*)&Q, (void*)&part, (void*)&outp};
        hipError_t err = hipLaunchCooperativeKernel(
            (const void*)fused_kernel, dim3(512), dim3(256), args, 0, stream);
        if (err == hipSuccess) return;
    }

    // -------- fallback: 3-kernel R5 path --------
    const size_t cap = ws_size / (slab * sizeof(float));
    int nchunk; float* fin = ws; float* part; bool do_reduce;
    if (cap >= 3) {
        size_t n = cap - 1; if (n > 16) n = 16;
        nchunk = (int)n; part = ws + slab; do_reduce = true;
    } else { nchunk = 1; part = ws; do_reduce = false; }
    const int Lc = (L_TOT + nchunk - 1) / nchunk;

    hipLaunchKernelGGL(kv_partial_kernel, dim3(nchunk, NBH), dim3(256), 0, stream,
                       K, V, part, Lc);
    if (do_reduce) {
        const int nb = ((NBH * KVSZ) / 4 + 255) / 256;
        hipLaunchKernelGGL(kv_reduce_kernel, dim3(nb), dim3(256), 0, stream,
                           part, fin, nchunk);
    }
    hipLaunchKernelGGL(attn_out_kernel, dim3(512), dim3(256), 0, stream,
                       Q, fin, outp);
}

// Round 8
// 64.173 us; speedup vs baseline: 2.8598x; 2.8598x over previous
//
#include <hip/hip_runtime.h>
#include <math.h>

// LinearAttention: L=4096, B=4, H=8, D=Dv=64, fp32.
// out[l,b,h,e] = (phiQ[l,bh,:] . kv[bh,:,e]) / (phiQ[l,bh,:] . ksum[bh,:] + eps)
// kv[bh,d,e] = sum_l phiK[l,bh,d] * V[l,bh,e]   (GLOBAL sum, not causal)
// phi(x) = elu(x)+1 = x>0 ? x+1 : exp(x)

#define L_TOT 4096
#define NBH   32            // B*H
#define ROWSTRIDE 2048      // B*H*D floats between consecutive l
#define KVSZ  4160          // 64*64 kv + 64 ksum
#define EPS_  1e-6f

__device__ __forceinline__ float phi_(float x) {
    return x > 0.0f ? x + 1.0f : __expf(x);
}

// ---------------- Pass 1 v2: partial kv + ksum ----------------
// grid = (nchunk=32, 32bh), block = 256 (4 waves). Double-buffered 32 KB LDS
// (2 x [32][64] phiK + [32][64] V), ONE barrier per 32-row tile, next-tile
// global loads issued before compute and consumed after it (latency hidden
// under the 8x8 FMA block). 32 KB -> 4 blocks/CU resident = 16 waves/CU.
// End: 3-round cross-wave reduce through buffer 0, wave 0 stores partial.
__global__ __launch_bounds__(256) void kv_partial_kernel(
    const float* __restrict__ K, const float* __restrict__ V,
    float* __restrict__ part, int Lc)
{
    __shared__ __align__(16) float sm[8192];   // 32 KB: buf b at sm + b*4096

    const int tid  = threadIdx.x;
    const int w    = tid >> 6;
    const int lane = tid & 63;
    const int c    = blockIdx.x;
    const int bh   = blockIdx.y;
    const int l0c  = c * Lc;
    const int lend = min(l0c + Lc, L_TOT);

    const int d0 = (lane >> 3) * 8;     // lane's 8 kv-rows (d)
    const int e0 = (lane & 7) * 8;      // lane's 8 kv-cols (e)
    const int sr = tid >> 4;            // staging row 0..15 (and +16)
    const int sc = (tid & 15) * 4;      // staging col (float4)
    const size_t bh_off = (size_t)bh * 64;

    float acc[8][8];
    #pragma unroll
    for (int i = 0; i < 8; ++i) {
        #pragma unroll
        for (int j = 0; j < 8; ++j) acc[i][j] = 0.f;
    }
    float ks[8] = {0.f,0.f,0.f,0.f,0.f,0.f,0.f,0.f};

    const float4 z4 = make_float4(0.f, 0.f, 0.f, 0.f);
    bool ok0 = (l0c + sr) < lend;
    bool ok1 = (l0c + sr + 16) < lend;
    float4 ka = z4, kb = z4, va = z4, vb = z4;
    if (ok0) {
        const size_t b = (size_t)(l0c + sr) * ROWSTRIDE + bh_off + sc;
        ka = *(const float4*)(K + b);  va = *(const float4*)(V + b);
    }
    if (ok1) {
        const size_t b = (size_t)(l0c + sr + 16) * ROWSTRIDE + bh_off + sc;
        kb = *(const float4*)(K + b);  vb = *(const float4*)(V + b);
    }
    {   // write tile 0 into buf 0  (phi(0)=1 trap: invalid rows store 0)
        float4 pa = z4, pq = z4;
        if (ok0) { pa.x = phi_(ka.x); pa.y = phi_(ka.y); pa.z = phi_(ka.z); pa.w = phi_(ka.w); }
        if (ok1) { pq.x = phi_(kb.x); pq.y = phi_(kb.y); pq.z = phi_(kb.z); pq.w = phi_(kb.w); }
        *(float4*)&sm[sr * 64 + sc]          = pa;
        *(float4*)&sm[(sr + 16) * 64 + sc]   = pq;
        *(float4*)&sm[2048 + sr * 64 + sc]        = va;
        *(float4*)&sm[2048 + (sr + 16) * 64 + sc] = vb;
    }
    __syncthreads();

    for (int t = 0; ; ++t) {
        float* __restrict__ bp = sm + (t & 1) * 4096;

        // issue next-tile loads (consumed AFTER compute)
        const int ln = l0c + (t + 1) * 32;
        const bool on = ln < lend;
        ok0 = (ln + sr) < lend;
        ok1 = (ln + sr + 16) < lend;
        ka = z4; kb = z4; va = z4; vb = z4;
        if (ok0) {
            const size_t b = (size_t)(ln + sr) * ROWSTRIDE + bh_off + sc;
            ka = *(const float4*)(K + b);  va = *(const float4*)(V + b);
        }
        if (ok1) {
            const size_t b = (size_t)(ln + sr + 16) * ROWSTRIDE + bh_off + sc;
            kb = *(const float4*)(K + b);  vb = *(const float4*)(V + b);
        }

        // compute this wave's 8 rows of the staged 32
        #pragma unroll
        for (int r = 0; r < 8; ++r) {
            const int rr = w * 8 + r;
            float4 a0 = *(const float4*)&bp[rr * 64 + d0];
            float4 a1 = *(const float4*)&bp[rr * 64 + d0 + 4];
            float4 b0 = *(const float4*)&bp[2048 + rr * 64 + e0];
            float4 b1 = *(const float4*)&bp[2048 + rr * 64 + e0 + 4];
            float av[8] = {a0.x,a0.y,a0.z,a0.w,a1.x,a1.y,a1.z,a1.w};
            float bv[8] = {b0.x,b0.y,b0.z,b0.w,b1.x,b1.y,b1.z,b1.w};
            #pragma unroll
            for (int i = 0; i < 8; ++i) {
                ks[i] += av[i];
                #pragma unroll
                for (int j = 0; j < 8; ++j)
                    acc[i][j] = fmaf(av[i], bv[j], acc[i][j]);
            }
        }

        if (!on) break;

        // write next tile into the other buffer (safe: its last readers
        // finished before the barrier that ended iteration t-1)
        float* __restrict__ np = sm + ((t + 1) & 1) * 4096;
        float4 pa = z4, pq = z4;
        if (ok0) { pa.x = phi_(ka.x); pa.y = phi_(ka.y); pa.z = phi_(ka.z); pa.w = phi_(ka.w); }
        if (ok1) { pq.x = phi_(kb.x); pq.y = phi_(kb.y); pq.z = phi_(kb.z); pq.w = phi_(kb.w); }
        *(float4*)&np[sr * 64 + sc]          = pa;
        *(float4*)&np[(sr + 16) * 64 + sc]   = pq;
        *(float4*)&np[2048 + sr * 64 + sc]        = va;
        *(float4*)&np[2048 + (sr + 16) * 64 + sc] = vb;
        __syncthreads();
    }

    // ---- cross-wave reduce, 3 sequential rounds through sm[0..4159] ----
    __syncthreads();
    #pragma unroll 1
    for (int k = 1; k < 4; ++k) {
        if (w == k) {
            #pragma unroll
            for (int i = 0; i < 8; ++i) {
                *(float4*)&sm[(d0 + i) * 64 + e0]     = make_float4(acc[i][0], acc[i][1], acc[i][2], acc[i][3]);
                *(float4*)&sm[(d0 + i) * 64 + e0 + 4] = make_float4(acc[i][4], acc[i][5], acc[i][6], acc[i][7]);
            }
            if (e0 == 0) {
                #pragma unroll
                for (int i = 0; i < 8; ++i) sm[4096 + d0 + i] = ks[i];
            }
        }
        __syncthreads();
        if (w == 0) {
            #pragma unroll
            for (int i = 0; i < 8; ++i) {
                float4 s0 = *(const float4*)&sm[(d0 + i) * 64 + e0];
                float4 s1 = *(const float4*)&sm[(d0 + i) * 64 + e0 + 4];
                acc[i][0] += s0.x; acc[i][1] += s0.y; acc[i][2] += s0.z; acc[i][3] += s0.w;
                acc[i][4] += s1.x; acc[i][5] += s1.y; acc[i][6] += s1.z; acc[i][7] += s1.w;
            }
            if (e0 == 0) {
                #pragma unroll
                for (int i = 0; i < 8; ++i) ks[i] += sm[4096 + d0 + i];
            }
        }
        __syncthreads();
    }

    if (w == 0) {
        float* pb = part + ((size_t)c * NBH + bh) * KVSZ;
        #pragma unroll
        for (int i = 0; i < 8; ++i) {
            *(float4*)&pb[(d0 + i) * 64 + e0]     = make_float4(acc[i][0], acc[i][1], acc[i][2], acc[i][3]);
            *(float4*)&pb[(d0 + i) * 64 + e0 + 4] = make_float4(acc[i][4], acc[i][5], acc[i][6], acc[i][7]);
        }
        if (e0 == 0) {
            #pragma unroll
            for (int i = 0; i < 8; ++i) pb[4096 + d0 + i] = ks[i];
        }
    }
}

// ---------------- Pass 1b: reduce partials (float4) ----------------
__global__ __launch_bounds__(256) void kv_reduce_kernel(
    const float* __restrict__ part, float* __restrict__ fin, int nchunk)
{
    const int i4 = blockIdx.x * 256 + threadIdx.x;
    if (i4 >= (NBH * KVSZ) / 4) return;
    const float4* p4 = (const float4*)part;
    float4 s = make_float4(0.f, 0.f, 0.f, 0.f);
    for (int cc = 0; cc < nchunk; ++cc) {
        float4 v = p4[(size_t)cc * (NBH * KVSZ / 4) + i4];
        s.x += v.x; s.y += v.y; s.z += v.z; s.w += v.w;
    }
    ((float4*)fin)[i4] = s;
}

// ---------------- Pass 2: register-tiled GEMM per wave, kv in LDS ----------
// grid = 512 (16 token-blocks x 32 bh), block = 256 (4 waves). Lane owns an
// 8tok x 8e tile. A (phiQ^T) from per-wave LDS with XOR swizzle keyed on
// (d>>2)&15: staging writes land 2-way per bank (free, m136); GEMM reads are
// same-row broadcasts (conflict-free for any swizzle). B from block-local
// LDS kv copy; ksum via uniform s_load. LDS 80 KB -> 2 blocks/CU.
__global__ __launch_bounds__(256) void attn_out_kernel(
    const float* __restrict__ Q, const float* __restrict__ fin,
    float* __restrict__ out)
{
    __shared__ __align__(16) float pqT[4][4096];   // 64 KB per-wave phiQ^T
    __shared__ __align__(16) float skv[4096];      // 16 KB kv[d][e]

    const int tid  = threadIdx.x;
    const int lane = tid & 63;
    const int w    = tid >> 6;
    const int bh   = blockIdx.x & 31;
    const int tile0 = (blockIdx.x >> 5) * 256 + w * 64;

    const float* __restrict__ fb = fin + (size_t)bh * KVSZ;
    float* __restrict__ pw = pqT[w];

    // copy kv table into LDS (1024 float4, coalesced)
    {
        const float4* __restrict__ fb4 = (const float4*)fb;
        float4* __restrict__ sk4 = (float4*)skv;
        #pragma unroll
        for (int k = 0; k < 4; ++k)
            sk4[tid + k * 256] = fb4[tid + k * 256];
    }

    // stage phi(Q)^T: token t = 4r+s stored in f4-block j' = r ^ ((d>>2)&15)
    {
        const int s  = lane >> 4;
        const int cq = (lane & 15) * 4;          // cq>>2 == lane&15 for all 4 writes
        const int xk = lane & 15;                // swizzle key for rows cq..cq+3
        #pragma unroll
        for (int r = 0; r < 16; ++r) {
            const int t = r * 4 + s;
            float4 q4 = *(const float4*)(Q + (size_t)(tile0 + t) * ROWSTRIDE
                                           + (size_t)bh * 64 + cq);
            const int jx = ((r ^ xk) << 2) + s;
            pw[(cq + 0) * 64 + jx] = phi_(q4.x);
            pw[(cq + 1) * 64 + jx] = phi_(q4.y);
            pw[(cq + 2) * 64 + jx] = phi_(q4.z);
            pw[(cq + 3) * 64 + jx] = phi_(q4.w);
        }
    }
    __syncthreads();

    const int t0 = (lane >> 3) * 8;      // lane's 8 tokens
    const int e0 = (lane & 7) * 8;       // lane's 8 e
    const int jb = t0 >> 2;              // even f4-block index

    float acc[8][8];
    #pragma unroll
    for (int i = 0; i < 8; ++i) {
        #pragma unroll
        for (int j = 0; j < 8; ++j) acc[i][j] = 0.f;
    }
    float den[8] = {0.f,0.f,0.f,0.f,0.f,0.f,0.f,0.f};

    #pragma unroll 4
    for (int d = 0; d < 64; ++d) {
        const int x = (d >> 2) & 15;
        float4 a0 = *(const float4*)&pw[d * 64 + ((jb       ^ x) << 2)];
        float4 a1 = *(const float4*)&pw[d * 64 + (((jb + 1) ^ x) << 2)];
        float4 b0 = *(const float4*)&skv[d * 64 + e0];
        float4 b1 = *(const float4*)&skv[d * 64 + e0 + 4];
        const float ksv = fb[4096 + d];          // uniform s_load
        float av[8] = {a0.x,a0.y,a0.z,a0.w,a1.x,a1.y,a1.z,a1.w};
        float bv[8] = {b0.x,b0.y,b0.z,b0.w,b1.x,b1.y,b1.z,b1.w};
        #pragma unroll
        for (int i = 0; i < 8; ++i) {
            den[i] = fmaf(av[i], ksv, den[i]);
            #pragma unroll
            for (int j = 0; j < 8; ++j)
                acc[i][j] = fmaf(av[i], bv[j], acc[i][j]);
        }
    }

    #pragma unroll
    for (int i = 0; i < 8; ++i) {
        const float inv = 1.0f / (den[i] + EPS_);
        float* op = out + (size_t)(tile0 + t0 + i) * ROWSTRIDE + (size_t)bh * 64 + e0;
        *(float4*)op       = make_float4(acc[i][0]*inv, acc[i][1]*inv,
                                         acc[i][2]*inv, acc[i][3]*inv);
        *(float4*)(op + 4) = make_float4(acc[i][4]*inv, acc[i][5]*inv,
                                         acc[i][6]*inv, acc[i][7]*inv);
    }
}

extern "C" void kernel_launch(void* const* d_in, const int* in_sizes, int n_in,
                              void* d_out, int out_size, void* d_ws, size_t ws_size,
                              hipStream_t stream) {
    const float* Q = (const float*)d_in[0];
    const float* K = (const float*)d_in[1];
    const float* V = (const float*)d_in[2];
    float* outp = (float*)d_out;
    float* ws   = (float*)d_ws;

    const size_t slab = (size_t)NBH * KVSZ;          // 133120 floats = 532 KB
    const size_t cap  = ws_size / (slab * sizeof(float));

    int nchunk;
    float* fin = ws;
    float* part;
    bool do_reduce;
    if (cap >= 3) {                 // final slab + >=2 partial slabs
        size_t n = cap - 1;
        if (n > 32) n = 32;         // 32 chunks -> 1024 blocks = 4/CU resident
        nchunk = (int)n;
        part = ws + slab;
        do_reduce = true;
    } else {                        // tiny ws: single chunk, write final directly
        nchunk = 1;
        part = ws;
        do_reduce = false;
    }
    const int Lc = (L_TOT + nchunk - 1) / nchunk;

    hipLaunchKernelGGL(kv_partial_kernel, dim3(nchunk, NBH), dim3(256), 0, stream,
                       K, V, part, Lc);
    if (do_reduce) {
        const int nb = ((NBH * KVSZ) / 4 + 255) / 256;
        hipLaunchKernelGGL(kv_reduce_kernel, dim3(nb), dim3(256), 0, stream,
                           part, fin, nchunk);
    }
    hipLaunchKernelGGL(attn_out_kernel, dim3(512), dim3(256), 0, stream,
                       Q, fin, outp);
}

// Round 9
// 58.316 us; speedup vs baseline: 3.1470x; 1.1004x over previous
//
#include <hip/hip_runtime.h>
#include <math.h>

// LinearAttention: L=4096, B=4, H=8, D=Dv=64, fp32.
// out[l,b,h,e] = (phiQ[l,bh,:] . kv[bh,:,e]) / (phiQ[l,bh,:] . ksum[bh,:] + eps)
// kv[bh,d,e] = sum_l phiK[l,bh,d] * V[l,bh,e]   (GLOBAL sum, not causal)
// phi(x) = elu(x)+1 = x>0 ? x+1 : exp(x)

#define L_TOT 4096
#define NBH   32            // B*H
#define ROWSTRIDE 2048      // B*H*D floats between consecutive l
#define KVSZ  4160          // 64*64 kv + 64 ksum
#define EPS_  1e-6f

__device__ __forceinline__ float phi_(float x) {
    return x > 0.0f ? x + 1.0f : __expf(x);
}

// ---------------- Pass 1: partial kv + ksum (R5 version) ----------------
// grid = (16, 32) = 512 blocks. 4 waves; each WAVE owns a full 64x64 kv
// accumulator (8x8 tile per lane); 4 ds_read_b128 per row per wave.
__global__ __launch_bounds__(256) void kv_partial_kernel(
    const float* __restrict__ K, const float* __restrict__ V,
    float* __restrict__ part, int Lc)
{
    __shared__ float sm[12480];                    // 48.75 KB
    float (*phk)[64] = (float(*)[64])sm;           // [32][64] staged phiK
    float (*vvv)[64] = (float(*)[64])(sm + 2048);  // [32][64] staged V

    const int tid  = threadIdx.x;
    const int w    = tid >> 6;
    const int lane = tid & 63;
    const int c    = blockIdx.x;
    const int bh   = blockIdx.y;
    const int l0c  = c * Lc;
    const int lend = min(l0c + Lc, L_TOT);

    const int d0 = (lane >> 3) * 8;
    const int e0 = (lane & 7) * 8;
    const int sr = tid >> 4;
    const int sc = (tid & 15) * 4;

    float acc[8][8];
    #pragma unroll
    for (int i = 0; i < 8; ++i) {
        #pragma unroll
        for (int j = 0; j < 8; ++j) acc[i][j] = 0.f;
    }
    float ks[8] = {0.f,0.f,0.f,0.f,0.f,0.f,0.f,0.f};

    const size_t bh_off = (size_t)bh * 64;

    float4 z4 = make_float4(0.f, 0.f, 0.f, 0.f);
    bool ok0 = (l0c + sr) < lend;
    bool ok1 = (l0c + sr + 16) < lend;
    float4 ka = z4, kb = z4, va = z4, vb = z4;
    if (ok0) {
        const size_t b = (size_t)(l0c + sr) * ROWSTRIDE + bh_off + sc;
        ka = *(const float4*)(K + b);  va = *(const float4*)(V + b);
    }
    if (ok1) {
        const size_t b = (size_t)(l0c + sr + 16) * ROWSTRIDE + bh_off + sc;
        kb = *(const float4*)(K + b);  vb = *(const float4*)(V + b);
    }

    for (int l0 = l0c; l0 < lend; l0 += 32) {
        float4 pa = z4, pb2 = z4;
        if (ok0) { pa.x  = phi_(ka.x); pa.y  = phi_(ka.y); pa.z  = phi_(ka.z); pa.w  = phi_(ka.w); }
        if (ok1) { pb2.x = phi_(kb.x); pb2.y = phi_(kb.y); pb2.z = phi_(kb.z); pb2.w = phi_(kb.w); }
        __syncthreads();
        *(float4*)&phk[sr][sc]      = pa;
        *(float4*)&phk[sr + 16][sc] = pb2;
        *(float4*)&vvv[sr][sc]      = va;
        *(float4*)&vvv[sr + 16][sc] = vb;
        __syncthreads();

        ok0 = (l0 + 32 + sr) < lend;
        ok1 = (l0 + 32 + sr + 16) < lend;
        ka = z4; kb = z4; va = z4; vb = z4;
        if (ok0) {
            const size_t b = (size_t)(l0 + 32 + sr) * ROWSTRIDE + bh_off + sc;
            ka = *(const float4*)(K + b);  va = *(const float4*)(V + b);
        }
        if (ok1) {
            const size_t b = (size_t)(l0 + 32 + sr + 16) * ROWSTRIDE + bh_off + sc;
            kb = *(const float4*)(K + b);  vb = *(const float4*)(V + b);
        }

        #pragma unroll
        for (int r = 0; r < 8; ++r) {
            const int rr = w * 8 + r;
            float4 a0 = *(const float4*)&phk[rr][d0];
            float4 a1 = *(const float4*)&phk[rr][d0 + 4];
            float4 b0 = *(const float4*)&vvv[rr][e0];
            float4 b1 = *(const float4*)&vvv[rr][e0 + 4];
            float av[8] = {a0.x,a0.y,a0.z,a0.w,a1.x,a1.y,a1.z,a1.w};
            float bv[8] = {b0.x,b0.y,b0.z,b0.w,b1.x,b1.y,b1.z,b1.w};
            #pragma unroll
            for (int i = 0; i < 8; ++i) {
                ks[i] += av[i];
                #pragma unroll
                for (int j = 0; j < 8; ++j)
                    acc[i][j] = fmaf(av[i], bv[j], acc[i][j]);
            }
        }
    }

    __syncthreads();
    if (w > 0) {
        float* sl = sm + (w - 1) * 4160;
        #pragma unroll
        for (int i = 0; i < 8; ++i) {
            *(float4*)&sl[(d0 + i) * 64 + e0]     = make_float4(acc[i][0], acc[i][1], acc[i][2], acc[i][3]);
            *(float4*)&sl[(d0 + i) * 64 + e0 + 4] = make_float4(acc[i][4], acc[i][5], acc[i][6], acc[i][7]);
        }
        if (e0 == 0) {
            #pragma unroll
            for (int i = 0; i < 8; ++i) sl[4096 + d0 + i] = ks[i];
        }
    }
    __syncthreads();
    if (w == 0) {
        float* pb = part + ((size_t)c * NBH + bh) * KVSZ;
        #pragma unroll
        for (int i = 0; i < 8; ++i) {
            #pragma unroll
            for (int jq = 0; jq < 2; ++jq) {
                const int off = (d0 + i) * 64 + e0 + jq * 4;
                float4 s0 = *(const float4*)&sm[off];
                float4 s1 = *(const float4*)&sm[4160 + off];
                float4 s2 = *(const float4*)&sm[8320 + off];
                float4 o;
                o.x = acc[i][jq*4+0] + s0.x + s1.x + s2.x;
                o.y = acc[i][jq*4+1] + s0.y + s1.y + s2.y;
                o.z = acc[i][jq*4+2] + s0.z + s1.z + s2.z;
                o.w = acc[i][jq*4+3] + s0.w + s1.w + s2.w;
                *(float4*)&pb[off] = o;
            }
        }
        if (e0 == 0) {
            #pragma unroll
            for (int i = 0; i < 8; ++i) {
                const int dd = 4096 + d0 + i;
                pb[dd] = ks[i] + sm[dd] + sm[4160 + dd] + sm[8320 + dd];
            }
        }
    }
}

// ---------------- Pass 1b: reduce partials (float4) ----------------
__global__ __launch_bounds__(256) void kv_reduce_kernel(
    const float* __restrict__ part, float* __restrict__ fin, int nchunk)
{
    const int i4 = blockIdx.x * 256 + threadIdx.x;
    if (i4 >= (NBH * KVSZ) / 4) return;
    const float4* p4 = (const float4*)part;
    float4 s = make_float4(0.f, 0.f, 0.f, 0.f);
    for (int cc = 0; cc < nchunk; ++cc) {
        float4 v = p4[(size_t)cc * (NBH * KVSZ / 4) + i4];
        s.x += v.x; s.y += v.y; s.z += v.z; s.w += v.w;
    }
    ((float4*)fin)[i4] = s;
}

// ---------------- Pass 2: register-tiled GEMM per wave ----------------
// Inner loop is now PURE DS + VALU: ksum comes from a per-lane register via
// v_readlane (no wait counter) instead of an in-loop s_load whose
// lgkmcnt(0) drain was serializing all in-flight ds_reads every iteration.
__global__ __launch_bounds__(256) void attn_out_kernel(
    const float* __restrict__ Q, const float* __restrict__ fin,
    float* __restrict__ out)
{
    __shared__ __align__(16) float pqT[4][4096];   // 64 KB per-wave phiQ^T
    __shared__ __align__(16) float skv[4096];      // 16 KB kv[d][e]

    const int tid  = threadIdx.x;
    const int lane = tid & 63;
    const int w    = tid >> 6;
    const int bh   = blockIdx.x & 31;
    const int tile0 = (blockIdx.x >> 5) * 256 + w * 64;

    const float* __restrict__ fb = fin + (size_t)bh * KVSZ;
    float* __restrict__ pw = pqT[w];

    // per-lane ksum (lane = d); broadcast in-loop via readlane
    const float kreg = fb[4096 + lane];

    // copy kv table into LDS (1024 float4, coalesced)
    {
        const float4* __restrict__ fb4 = (const float4*)fb;
        float4* __restrict__ sk4 = (float4*)skv;
        #pragma unroll
        for (int k = 0; k < 4; ++k)
            sk4[tid + k * 256] = fb4[tid + k * 256];
    }

    // stage phi(Q)^T: token t = 4r+s stored in f4-block j' = r ^ ((d>>2)&15)
    {
        const int s  = lane >> 4;
        const int cq = (lane & 15) * 4;
        const int xk = lane & 15;
        #pragma unroll
        for (int r = 0; r < 16; ++r) {
            const int t = r * 4 + s;
            float4 q4 = *(const float4*)(Q + (size_t)(tile0 + t) * ROWSTRIDE
                                           + (size_t)bh * 64 + cq);
            const int jx = ((r ^ xk) << 2) + s;
            pw[(cq + 0) * 64 + jx] = phi_(q4.x);
            pw[(cq + 1) * 64 + jx] = phi_(q4.y);
            pw[(cq + 2) * 64 + jx] = phi_(q4.z);
            pw[(cq + 3) * 64 + jx] = phi_(q4.w);
        }
    }
    __syncthreads();

    const int t0 = (lane >> 3) * 8;
    const int e0 = (lane & 7) * 8;
    const int jb = t0 >> 2;

    float acc[8][8];
    #pragma unroll
    for (int i = 0; i < 8; ++i) {
        #pragma unroll
        for (int j = 0; j < 8; ++j) acc[i][j] = 0.f;
    }
    float den[8] = {0.f,0.f,0.f,0.f,0.f,0.f,0.f,0.f};

    #pragma unroll 4
    for (int d = 0; d < 64; ++d) {
        const int x = (d >> 2) & 15;
        float4 a0 = *(const float4*)&pw[d * 64 + ((jb       ^ x) << 2)];
        float4 a1 = *(const float4*)&pw[d * 64 + (((jb + 1) ^ x) << 2)];
        float4 b0 = *(const float4*)&skv[d * 64 + e0];
        float4 b1 = *(const float4*)&skv[d * 64 + e0 + 4];
        // wave-uniform ksum[d] without memory: v_readlane_b32 (no lgkmcnt)
        const float ksv = __uint_as_float(
            __builtin_amdgcn_readlane(__float_as_uint(kreg), d));
        float av[8] = {a0.x,a0.y,a0.z,a0.w,a1.x,a1.y,a1.z,a1.w};
        float bv[8] = {b0.x,b0.y,b0.z,b0.w,b1.x,b1.y,b1.z,b1.w};
        #pragma unroll
        for (int i = 0; i < 8; ++i) {
            den[i] = fmaf(av[i], ksv, den[i]);
            #pragma unroll
            for (int j = 0; j < 8; ++j)
                acc[i][j] = fmaf(av[i], bv[j], acc[i][j]);
        }
    }

    #pragma unroll
    for (int i = 0; i < 8; ++i) {
        const float inv = 1.0f / (den[i] + EPS_);
        float* op = out + (size_t)(tile0 + t0 + i) * ROWSTRIDE + (size_t)bh * 64 + e0;
        *(float4*)op       = make_float4(acc[i][0]*inv, acc[i][1]*inv,
                                         acc[i][2]*inv, acc[i][3]*inv);
        *(float4*)(op + 4) = make_float4(acc[i][4]*inv, acc[i][5]*inv,
                                         acc[i][6]*inv, acc[i][7]*inv);
    }
}

extern "C" void kernel_launch(void* const* d_in, const int* in_sizes, int n_in,
                              void* d_out, int out_size, void* d_ws, size_t ws_size,
                              hipStream_t stream) {
    const float* Q = (const float*)d_in[0];
    const float* K = (const float*)d_in[1];
    const float* V = (const float*)d_in[2];
    float* outp = (float*)d_out;
    float* ws   = (float*)d_ws;

    const size_t slab = (size_t)NBH * KVSZ;          // 133120 floats = 532 KB
    const size_t cap  = ws_size / (slab * sizeof(float));

    int nchunk;
    float* fin = ws;
    float* part;
    bool do_reduce;
    if (cap >= 3) {
        size_t n = cap - 1;
        if (n > 16) n = 16;
        nchunk = (int)n;
        part = ws + slab;
        do_reduce = true;
    } else {
        nchunk = 1;
        part = ws;
        do_reduce = false;
    }
    const int Lc = (L_TOT + nchunk - 1) / nchunk;

    hipLaunchKernelGGL(kv_partial_kernel, dim3(nchunk, NBH), dim3(256), 0, stream,
                       K, V, part, Lc);
    if (do_reduce) {
        const int nb = ((NBH * KVSZ) / 4 + 255) / 256;
        hipLaunchKernelGGL(kv_reduce_kernel, dim3(nb), dim3(256), 0, stream,
                           part, fin, nchunk);
    }
    hipLaunchKernelGGL(attn_out_kernel, dim3(512), dim3(256), 0, stream,
                       Q, fin, outp);
}